// Round 1
// baseline (484.572 us; speedup 1.0000x reference)
//
#include <hip/hip_runtime.h>

#define BB 16
#define SS 512
#define KIN 512
#define H 256

constexpr float DECAY = 0.951229424500714f;    // exp(-1/20), both tau=20
constexpr float OMD   = 0.048770575499286f;    // 1 - exp(-1/20)
constexpr float LR    = 0.01f;
constexpr float WMAX  = 1.0f;

__device__ __forceinline__ float fast_tanh(float x) {
    float e = __expf(2.f * x);
    return 1.f - __fdividef(2.f, e + 1.f);
}

// OUT[m][n] = sum_k X[m][k] * W[n][k];  X:[8192,512], W:[512,512], OUT:[8192,512]
__global__ __launch_bounds__(256) void gemm_xwT(const float* __restrict__ X,
                                                const float* __restrict__ W,
                                                float* __restrict__ OUT) {
    __shared__ float As[16][68];
    __shared__ float Bs[16][68];
    const int m0 = blockIdx.y * 64;
    const int n0 = blockIdx.x * 64;
    const int tid = threadIdx.x;
    const int r  = tid >> 2;   // 0..63
    const int cg = tid & 3;    // 0..3
    const int tx = tid & 15;   // n sub
    const int ty = tid >> 4;   // m sub
    float acc[4][4] = {};
    for (int k0 = 0; k0 < KIN; k0 += 16) {
        float4 av = *(const float4*)&X[(size_t)(m0 + r) * KIN + k0 + cg * 4];
        float4 bv = *(const float4*)&W[(size_t)(n0 + r) * KIN + k0 + cg * 4];
        __syncthreads();
        As[cg*4+0][r] = av.x; As[cg*4+1][r] = av.y; As[cg*4+2][r] = av.z; As[cg*4+3][r] = av.w;
        Bs[cg*4+0][r] = bv.x; Bs[cg*4+1][r] = bv.y; Bs[cg*4+2][r] = bv.z; Bs[cg*4+3][r] = bv.w;
        __syncthreads();
#pragma unroll
        for (int kk = 0; kk < 16; ++kk) {
            float4 a = *(const float4*)&As[kk][ty * 4];
            float4 b = *(const float4*)&Bs[kk][tx * 4];
            float ar[4] = {a.x, a.y, a.z, a.w};
            float br[4] = {b.x, b.y, b.z, b.w};
#pragma unroll
            for (int i = 0; i < 4; ++i)
#pragma unroll
                for (int j = 0; j < 4; ++j) acc[i][j] += ar[i] * br[j];
        }
    }
#pragma unroll
    for (int i = 0; i < 4; ++i) {
        float4 o = make_float4(acc[i][0], acc[i][1], acc[i][2], acc[i][3]);
        *(float4*)&OUT[(size_t)(m0 + ty * 4 + i) * KIN + n0 + tx * 4] = o;
    }
}

// cur: [B, S, 512] (ik = [:,:,0:256], iv = [:,:,256:512])
// One wave per mem-row; 4 waves (rows) per block; 64 blocks per batch.
__global__ __launch_bounds__(256) void scan_kernel(const float* __restrict__ cur,
                                                   float* __restrict__ mem_out,
                                                   float* __restrict__ keys,
                                                   float* __restrict__ vals) {
    const int b    = blockIdx.x >> 6;
    const int rg   = blockIdx.x & 63;
    const int tid  = threadIdx.x;
    const int wave = tid >> 6;
    const int lane = tid & 63;
    const int row  = rg * 4 + wave;

    __shared__ float key_lds[2][256];

    const float* curb = cur + (size_t)b * SS * 512;
    float* keyout = keys + (size_t)b * SS * H;
    float* valout = vals + (size_t)b * SS * H;

    float mem[4] = {0.f, 0.f, 0.f, 0.f};
    float ktr[4] = {0.f, 0.f, 0.f, 0.f};
    float kv = 0.f, vv = 0.f, vt = 0.f;

    // prefetch t=0 currents
    float ikt = curb[tid];
    float ivt = curb[256 + row];

    for (int t = 0; t < SS; ++t) {
        // key dynamics: thread tid owns column tid
        kv = DECAY * kv + ikt;
        float keyv = fast_tanh(kv);
        key_lds[t & 1][tid] = keyv;
        if (rg == 0) keyout[t * H + tid] = keyv;

        // prefetch next step's currents (in flight across the barrier)
        float ikn = 0.f, ivn = 0.f;
        if (t + 1 < SS) {
            const float* curn = curb + (size_t)(t + 1) * 512;
            ikn = curn[tid];
            ivn = curn[256 + row];
        }

        __syncthreads();

        // memory readout: this wave's row dotted with key
        float4 kc = *(const float4*)&key_lds[t & 1][lane * 4];
        float p = mem[0] * kc.x + mem[1] * kc.y + mem[2] * kc.z + mem[3] * kc.w;
#pragma unroll
        for (int off = 32; off > 0; off >>= 1) p += __shfl_xor(p, off);
        float ikv = 0.2f * p;

        // value dynamics (redundant across the 64 lanes of the row-wave)
        vv = DECAY * vv + ivt + ikv;
        float valv = fast_tanh(vv);
        vt = DECAY * vt + OMD * valv;
        if (lane == 0) valout[t * H + row] = valv;

        // traces + soft-bounded Hebbian update for this lane's 4 columns
        float c = LR * vt;
        float kr[4] = {kc.x, kc.y, kc.z, kc.w};
#pragma unroll
        for (int q = 0; q < 4; ++q) {
            ktr[q] = DECAY * ktr[q] + OMD * kr[q];
            mem[q] += c * ktr[q] * (WMAX - mem[q]);
        }

        ikt = ikn;
        ivt = ivn;
    }

    float4 mo = make_float4(mem[0], mem[1], mem[2], mem[3]);
    *(float4*)&mem_out[((size_t)b * H + row) * H + lane * 4] = mo;
}

extern "C" void kernel_launch(void* const* d_in, const int* in_sizes, int n_in,
                              void* d_out, int out_size, void* d_ws, size_t ws_size,
                              hipStream_t stream) {
    const float* x = (const float*)d_in[0];   // [B, S, IN] f32
    const float* W = (const float*)d_in[1];   // [2H, IN] f32
    float* out = (float*)d_out;
    float* mem_out = out;                               // [B, H, H]
    float* keys = out + (size_t)BB * H * H;             // [B, S, H]
    float* vals = keys + (size_t)BB * SS * H;           // [B, S, H]
    float* cur = (float*)d_ws;                          // [B, S, 512] = 16 MB

    dim3 gb(8, 128);  // N/64, M/64  (M = B*S = 8192, N = 2H = 512)
    gemm_xwT<<<gb, 256, 0, stream>>>(x, W, cur);
    scan_kernel<<<1024, 256, 0, stream>>>(cur, mem_out, keys, vals);
}